// Round 4
// baseline (114.157 us; speedup 1.0000x reference)
//
#include <hip/hip_runtime.h>

// out[b,n] = q^T W_n p ; p=emb[b,row(n)], q=emb[b,col(n)], W_n=kern[:,n,:]
// R4: occupancy-first. No LDS. One wave = one (n, 16b) tile; block = 4 waves
// sharing n (W L1-reuse). Prep kernels convert kern AND emb to bf16 in d_ws.
// XCD-bijective grid: each XCD owns a 256-b emb slice (1MB bf16, L2-resident,
// reused 496x) and streams W through its L2 once (4MB).

#define B_TOT 2048
#define NF    32
#define EMB   64
#define NP    496

typedef short bf16x8 __attribute__((ext_vector_type(8)));
typedef short bf16x4 __attribute__((ext_vector_type(4)));
typedef float f32x4  __attribute__((ext_vector_type(4)));

static __device__ inline unsigned f2bf(float f) {          // RNE f32->bf16
    unsigned u = __builtin_bit_cast(unsigned, f);
    u += 0x7fffu + ((u >> 16) & 1u);
    return u >> 16;
}
static __device__ inline unsigned pack2(float lo, float hi) {
    return f2bf(lo) | (f2bf(hi) << 16);
}
static __device__ inline float bf2f(short s) {
    return __builtin_bit_cast(float, (unsigned)((unsigned short)s) << 16);
}

// kern f32 [h][n][e] -> bf16 [n][h][e]
__global__ __launch_bounds__(256) void cvt_kern(const float* __restrict__ kern,
                                                unsigned* __restrict__ kb) {
    const int i = (blockIdx.x * 256 + threadIdx.x) * 4;    // [n][h][e] elem idx
    const int n = i >> 12, h = (i >> 6) & 63, e = i & 63;
    const f32x4 v = *(const f32x4*)(kern + ((size_t)h * NP + n) * EMB + e);
    uint2 w;
    w.x = pack2(v[0], v[1]);
    w.y = pack2(v[2], v[3]);
    *(uint2*)(kb + (i >> 1)) = w;
}

// emb f32 -> bf16, same [b][f][e] layout
__global__ __launch_bounds__(256) void cvt_emb(const float* __restrict__ emb,
                                               unsigned* __restrict__ eb) {
    const int i = (blockIdx.x * 256 + threadIdx.x) * 8;
    const f32x4 v0 = *(const f32x4*)(emb + i);
    const f32x4 v1 = *(const f32x4*)(emb + i + 4);
    uint4 w;
    w.x = pack2(v0[0], v0[1]); w.y = pack2(v0[2], v0[3]);
    w.z = pack2(v1[0], v1[1]); w.w = pack2(v1[2], v1[3]);
    *(uint4*)(eb + (i >> 1)) = w;
}

template<bool EB>
__global__ __launch_bounds__(256) void opnl_main(
    const float* __restrict__ emb,   // [B][NF][EMB] f32
    const short* __restrict__ ebb,   // [B][NF][EMB] bf16 (if EB)
    const short* __restrict__ kb,    // [NP][64][64] bf16
    float* __restrict__ out)         // [B][NP] f32
{
    const int xcd = blockIdx.x & 7;          // bid%8 -> XCD (round-robin)
    const int j   = blockIdx.x >> 3;         // 0..1983 per XCD
    const int n   = j >> 2;                  // bt fastest, n next (W window small)
    const int bt  = j & 3;

    const int lane = threadIdx.x & 63;
    const int wid  = threadIdx.x >> 6;
    const int lo4  = lane & 15;
    const int hi4  = lane >> 4;
    const int b    = xcd * 256 + bt * 64 + wid * 16 + lo4;

    // decode n -> (r, c)  (np.triu_indices order)
    int r = 0, rem = n;
    while (rem >= NF - 1 - r) { rem -= NF - 1 - r; ++r; }
    const int c = r + 1 + rem;

    // W_n A-fragments: h = mh*16+lo4, e = kc*32 + hi4*8 + j  (L1-shared by 4 waves)
    bf16x8 wf[4][2];
    const bf16x8* wp = (const bf16x8*)(kb + (size_t)n * (EMB * EMB));
#pragma unroll
    for (int mh = 0; mh < 4; ++mh)
#pragma unroll
        for (int kc = 0; kc < 2; ++kc)
            wf[mh][kc] = wp[((mh * 16 + lo4) * 64 + kc * 32 + hi4 * 8) >> 3];

    // p B-fragments: p[b, e], e = kc*32 + hi4*8 + j
    bf16x8 pf[2];
    if constexpr (EB) {
        const short* pe = ebb + ((size_t)b * NF + r) * EMB + hi4 * 8;
#pragma unroll
        for (int kc = 0; kc < 2; ++kc)
            pf[kc] = *(const bf16x8*)(pe + kc * 32);
    } else {
        const float* pe = emb + ((size_t)b * NF + r) * EMB + hi4 * 8;
#pragma unroll
        for (int kc = 0; kc < 2; ++kc) {
            const f32x4 a = *(const f32x4*)(pe + kc * 32);
            const f32x4 d = *(const f32x4*)(pe + kc * 32 + 4);
            bf16x8 t;
            t[0] = (short)f2bf(a[0]); t[1] = (short)f2bf(a[1]);
            t[2] = (short)f2bf(a[2]); t[3] = (short)f2bf(a[3]);
            t[4] = (short)f2bf(d[0]); t[5] = (short)f2bf(d[1]);
            t[6] = (short)f2bf(d[2]); t[7] = (short)f2bf(d[3]);
            pf[kc] = t;
        }
    }

    f32x4 acc[4] = {f32x4{0,0,0,0}, f32x4{0,0,0,0},
                    f32x4{0,0,0,0}, f32x4{0,0,0,0}};
#pragma unroll
    for (int mh = 0; mh < 4; ++mh)
#pragma unroll
        for (int kc = 0; kc < 2; ++kc)
            acc[mh] = __builtin_amdgcn_mfma_f32_16x16x32_bf16(
                wf[mh][kc], pf[kc], acc[mh], 0, 0, 0);

    // epilogue: lane holds U[h = mh*16 + hi4*4 + reg, b]; dot with q[b,h]
    float val = 0.f;
#pragma unroll
    for (int mh = 0; mh < 4; ++mh) {
        if constexpr (EB) {
            const short* qe = ebb + ((size_t)b * NF + c) * EMB + mh * 16 + hi4 * 4;
            const bf16x4 q = *(const bf16x4*)qe;
            val += acc[mh][0] * bf2f(q[0]) + acc[mh][1] * bf2f(q[1])
                 + acc[mh][2] * bf2f(q[2]) + acc[mh][3] * bf2f(q[3]);
        } else {
            const f32x4 q = *(const f32x4*)(emb + ((size_t)b * NF + c) * EMB + mh * 16 + hi4 * 4);
            val += acc[mh][0] * q[0] + acc[mh][1] * q[1]
                 + acc[mh][2] * q[2] + acc[mh][3] * q[3];
        }
    }
    val += __shfl_xor(val, 16, 64);
    val += __shfl_xor(val, 32, 64);
    if (lane < 16) out[(size_t)b * NP + n] = val;
}

extern "C" void kernel_launch(void* const* d_in, const int* in_sizes, int n_in,
                              void* d_out, int out_size, void* d_ws, size_t ws_size,
                              hipStream_t stream) {
    const float* emb  = (const float*)d_in[0];   // 2048*32*64
    const float* kern = (const float*)d_in[1];   // 64*496*64
    float*       out  = (float*)d_out;           // 2048*496

    const size_t kb_bytes = (size_t)NP * EMB * EMB * 2;      // ~3.9 MB
    const size_t eb_bytes = (size_t)B_TOT * NF * EMB * 2;    // 8 MB
    unsigned* kb  = (unsigned*)d_ws;
    short*    ebb = (short*)((char*)d_ws + kb_bytes);
    const bool eb_ok = ws_size >= kb_bytes + eb_bytes;

    cvt_kern<<<(NP * EMB * EMB) / (256 * 4), 256, 0, stream>>>(kern, kb);   // 1984
    if (eb_ok)
        cvt_emb<<<(B_TOT * NF * EMB) / (256 * 8), 256, 0, stream>>>(emb, (unsigned*)ebb); // 2048

    const int grid = 8 * 4 * NP;   // 15872 blocks, nwg%8==0 (bijective XCD map)
    if (eb_ok)
        opnl_main<true ><<<grid, 256, 0, stream>>>(emb, ebb, (const short*)kb, out);
    else
        opnl_main<false><<<grid, 256, 0, stream>>>(emb, nullptr, (const short*)kb, out);
}

// Round 5
// 35.078 us; speedup vs baseline: 3.2544x; 3.2544x over previous
//
#include <hip/hip_runtime.h>

// out[b,n] = q^T W_n p ; p=emb[b,R(n)], q=emb[b,C(n)], W_n=kern[:,n,:]
// R5: kill scattered global loads.
//  - prep writes W in MFMA-fragment order -> W loads are coalesced 1KB/wave.
//  - octet-pair blocking: block stages 16 fields x 32 b (bf16, pad-72) in 72KB
//    LDS; covers its field-group's pairs. 512-thr blocks, 2/CU, 4 waves/SIMD.
//  - W in regs, reused for 2 x 16-b subtiles; p/q via LDS (cheap transpose).

#define B_TOT 2048
#define NF    32
#define EMB   64
#define NP    496
#define BT    32            // b per block
#define ESTR  72            // LDS row stride in shorts (64 + 8 pad)

typedef short bf16x8 __attribute__((ext_vector_type(8)));
typedef short bf16x4 __attribute__((ext_vector_type(4)));
typedef float f32x4  __attribute__((ext_vector_type(4)));

static __device__ inline unsigned f2bf(float f) {          // RNE f32->bf16
    unsigned u = __builtin_bit_cast(unsigned, f);
    u += 0x7fffu + ((u >> 16) & 1u);
    return u >> 16;
}
static __device__ inline unsigned pack2(float lo, float hi) {
    return f2bf(lo) | (f2bf(hi) << 16);
}
static __device__ inline float bf2f(short s) {
    return __builtin_bit_cast(float, (unsigned)((unsigned short)s) << 16);
}

// prep: kern f32 [h][n][e] -> bf16 fragment-ordered kb[n][frag][lane][8]
// frag = mh*2+kc ; lane l holds W[h=mh*16+(l&15)][e=kc*32+(l>>4)*8+j], j=0..7
__global__ __launch_bounds__(256) void cvt_frag(const float* __restrict__ kern,
                                                short* __restrict__ kb) {
    const int t    = blockIdx.x * 256 + threadIdx.x;   // 0 .. 496*512-1
    const int n    = t >> 9;
    const int frag = (t >> 6) & 7;
    const int l    = t & 63;
    const int h  = (frag >> 1) * 16 + (l & 15);
    const int e0 = (frag & 1) * 32 + (l >> 4) * 8;
    const float* src = kern + ((size_t)h * NP + n) * EMB + e0;
    const f32x4 a = *(const f32x4*)src;
    const f32x4 b = *(const f32x4*)(src + 4);
    uint4 w;
    w.x = pack2(a[0], a[1]); w.y = pack2(a[2], a[3]);
    w.z = pack2(b[0], b[1]); w.w = pack2(b[2], b[3]);
    *(uint4*)(kb + (size_t)t * 8) = w;                 // coalesced 16B/thread
}

__global__ __launch_bounds__(512, 4) void opnl_main(
    const float* __restrict__ emb,   // [B][NF][EMB] f32
    const short* __restrict__ kb,    // [NP][8][64][8] bf16 fragment order
    float* __restrict__ out)         // [B][NP] f32
{
    __shared__ short elds[16 * BT * ESTR];   // 16 fields x 32 b x 72 = 72KB

    const int g  = blockIdx.x >> 6;          // field-group 0..5
    const int bt = blockIdx.x & 63;          // b-tile 0..63
    const int b0 = bt * BT;

    // octet pair for this group: g<2 -> (2g, 2g+1); else (g2>>1, 2+(g2&1))
    const int g2  = g - 2;
    const int oi  = (g < 2) ? 2 * g     : (g2 >> 1);
    const int oj  = (g < 2) ? 2 * g + 1 : 2 + (g2 & 1);
    const int npr = (g < 2) ? 120 : 64;      // cross 64 (+ 2x28 within for g<2)

    // ---- stage emb[b0..b0+31][16 group fields][64] f32 -> bf16 LDS
    {
        const int sb = threadIdx.x >> 4;          // 0..31 (b)
        const int e4 = threadIdx.x & 15;          // e = e4*4
#pragma unroll
        for (int f = 0; f < 16; ++f) {
            const int gf = (f < 8) ? oi * 8 + f : oj * 8 + (f - 8);
            const f32x4 v = *(const f32x4*)(emb + ((size_t)(b0 + sb) * NF + gf) * EMB + e4 * 4);
            uint2 w;
            w.x = pack2(v[0], v[1]);
            w.y = pack2(v[2], v[3]);
            *(uint2*)&elds[(f * BT + sb) * ESTR + e4 * 4] = w;
        }
    }
    __syncthreads();

    const int lane = threadIdx.x & 63;
    const int wid  = threadIdx.x >> 6;       // 0..7
    const int lo4  = lane & 15;
    const int hi4  = lane >> 4;

    for (int pi = wid; pi < npr; pi += 8) {
        // pair index -> local fields (lr, lc)
        int lr, lc;
        if (pi < 64) { lr = pi >> 3; lc = 8 + (pi & 7); }          // cross
        else {
            int k = pi - 64, base = 0;                              // within
            if (k >= 28) { k -= 28; base = 8; }
            int r = 0;
            while (k >= 7 - r) { k -= 7 - r; ++r; }
            lr = base + r; lc = base + r + 1 + k;
        }
        const int R = (lr < 8) ? oi * 8 + lr : oj * 8 + (lr - 8);
        const int C = (lc < 8) ? oi * 8 + lc : oj * 8 + (lc - 8);
        const int n = R * (63 - R) / 2 + (C - R - 1);               // triu idx

        // W fragments: 8 coalesced 1KB loads
        bf16x8 wf[4][2];
        const bf16x8* wp = (const bf16x8*)(kb + (size_t)n * 4096);
#pragma unroll
        for (int mh = 0; mh < 4; ++mh)
#pragma unroll
            for (int kc = 0; kc < 2; ++kc)
                wf[mh][kc] = wp[(mh * 2 + kc) * 64 + lane];

#pragma unroll
        for (int sub = 0; sub < 2; ++sub) {
            const int bb = sub * 16 + lo4;   // local b (N-col = lo4)

            bf16x8 pf[2];
#pragma unroll
            for (int kc = 0; kc < 2; ++kc)
                pf[kc] = *(const bf16x8*)&elds[(lr * BT + bb) * ESTR + kc * 32 + hi4 * 8];

            f32x4 acc[4] = {f32x4{0,0,0,0}, f32x4{0,0,0,0},
                            f32x4{0,0,0,0}, f32x4{0,0,0,0}};
#pragma unroll
            for (int mh = 0; mh < 4; ++mh)
#pragma unroll
                for (int kc = 0; kc < 2; ++kc)
                    acc[mh] = __builtin_amdgcn_mfma_f32_16x16x32_bf16(
                        wf[mh][kc], pf[kc], acc[mh], 0, 0, 0);

            // out[b] = sum_h U[h,b] q[b,h]; lane holds h = mh*16 + hi4*4 + j
            float val = 0.f;
#pragma unroll
            for (int mh = 0; mh < 4; ++mh) {
                const bf16x4 q = *(const bf16x4*)&elds[(lc * BT + bb) * ESTR + mh * 16 + hi4 * 4];
                val += acc[mh][0] * bf2f(q[0]) + acc[mh][1] * bf2f(q[1])
                     + acc[mh][2] * bf2f(q[2]) + acc[mh][3] * bf2f(q[3]);
            }
            val += __shfl_xor(val, 16, 64);
            val += __shfl_xor(val, 32, 64);
            if (lane < 16) out[(size_t)(b0 + bb) * NP + n] = val;
        }
    }
}

extern "C" void kernel_launch(void* const* d_in, const int* in_sizes, int n_in,
                              void* d_out, int out_size, void* d_ws, size_t ws_size,
                              hipStream_t stream) {
    const float* emb  = (const float*)d_in[0];   // 2048*32*64
    const float* kern = (const float*)d_in[1];   // 64*496*64
    float*       out  = (float*)d_out;           // 2048*496
    short*       kb   = (short*)d_ws;            // 496*4096 bf16 ~ 3.9MB

    cvt_frag<<<(NP * 512) / 256, 256, 0, stream>>>(kern, kb);   // 992 blocks

    opnl_main<<<6 * 64, 512, 0, stream>>>(emb, kb, out);        // 384 blocks
}

// Round 6
// 30.415 us; speedup vs baseline: 3.7533x; 1.1533x over previous
//
#include <hip/hip_runtime.h>

// out[b,n] = q^T W_n p ; p=emb[b,R(n)], q=emb[b,C(n)], W_n=kern[:,n,:]
// R6: balanced schedule + W double-buffer.
//  - 8 block types x 64 b-tiles = 512 blocks (exactly 2/CU), 512 thr.
//    types 0-3: 16 contiguous fields (0..15 or 16..31), 60 triu16-pairs each;
//    types 4-7: octet-cross groups, 64 pairs each. Every wave: exactly 8 pairs.
//  - W fragment-ordered in d_ws (coalesced 1KB wave loads), ping-pong
//    double-buffered across the pair loop (static buffer choice, full unroll).
//  - p/q staged 16 fields x 32 b bf16 in 72KB LDS (pad-72).
//  - cvt: per-n block, coalesced reads -> LDS transpose -> coalesced writes.

#define B_TOT 2048
#define NF    32
#define EMB   64
#define NP    496
#define BT    32
#define ESTR  72

typedef short bf16x8 __attribute__((ext_vector_type(8)));
typedef short bf16x4 __attribute__((ext_vector_type(4)));
typedef float f32x4  __attribute__((ext_vector_type(4)));

static __device__ inline unsigned f2bf(float f) {          // RNE f32->bf16
    unsigned u = __builtin_bit_cast(unsigned, f);
    u += 0x7fffu + ((u >> 16) & 1u);
    return u >> 16;
}
static __device__ inline unsigned pack2(float lo, float hi) {
    return f2bf(lo) | (f2bf(hi) << 16);
}
static __device__ inline float bf2f(short s) {
    return __builtin_bit_cast(float, (unsigned)((unsigned short)s) << 16);
}

// ---- prep: kern f32 [h][n][e] -> bf16 fragment order kb[n][frag][lane][8]
// frag = mh*2+kc ; lane l holds W[h=mh*16+(l&15)][e=kc*32+(l>>4)*8+j]
__global__ __launch_bounds__(256) void cvt2(const float* __restrict__ kern,
                                            short* __restrict__ kb) {
    const int n = blockIdx.x;                 // 496 blocks
    __shared__ short w[EMB * ESTR];
#pragma unroll
    for (int j = 0; j < 4; ++j) {
        const int idx = threadIdx.x + 256 * j;        // (h, e4)
        const int h = idx >> 4, e4 = idx & 15;
        const f32x4 v = *(const f32x4*)(kern + ((size_t)h * NP + n) * EMB + e4 * 4);
        uint2 u;
        u.x = pack2(v[0], v[1]);
        u.y = pack2(v[2], v[3]);
        *(uint2*)&w[h * ESTR + e4 * 4] = u;
    }
    __syncthreads();
#pragma unroll
    for (int j = 0; j < 2; ++j) {
        const int u    = threadIdx.x + 256 * j;       // 0..511 fragment-lane units
        const int frag = u >> 6, l = u & 63;
        const int h  = (frag >> 1) * 16 + (l & 15);
        const int e0 = (frag & 1) * 32 + (l >> 4) * 8;
        const bf16x8 t = *(const bf16x8*)&w[h * ESTR + e0];
        *(bf16x8*)(kb + (size_t)n * 4096 + u * 8) = t;   // coalesced 16B
    }
}

__global__ __launch_bounds__(512, 4) void opnl_main(
    const float* __restrict__ emb,   // [B][NF][EMB] f32
    const short* __restrict__ kb,    // [NP][8][64][8] bf16 fragment order
    float* __restrict__ out)         // [B][NP] f32
{
    __shared__ short elds[16 * BT * ESTR];   // 72KB

    const int type = blockIdx.x >> 6;        // 0..7
    const int bt   = blockIdx.x & 63;        // bid%8 = bt%8 -> b-slice per XCD
    const int b0   = bt * BT;

    // staged-field bases: gf = f + (f<8 ? bLo : bHi)
    int bLo, bHi, npr;
    switch (type) {
        case 0: case 1: bLo = 0;  bHi = 0;  npr = 60; break;  // fields 0..15
        case 2: case 3: bLo = 16; bHi = 16; npr = 60; break;  // fields 16..31
        case 4:         bLo = 0;  bHi = 8;  npr = 64; break;  // O0 x O2
        case 5:         bLo = 8;  bHi = 16; npr = 64; break;  // O1 x O3
        case 6:         bLo = 0;  bHi = 16; npr = 64; break;  // O0 x O3
        default:        bLo = 8;  bHi = 8;  npr = 64; break;  // O1 x O2
    }

    // ---- stage emb[b0..b0+31][16 fields][64] f32 -> bf16 LDS
    {
        const int sb = threadIdx.x >> 4;          // 0..31
        const int e4 = threadIdx.x & 15;
#pragma unroll
        for (int f = 0; f < 16; ++f) {
            const int gf = f + (f < 8 ? bLo : bHi);
            const f32x4 v = *(const f32x4*)(emb + ((size_t)(b0 + sb) * NF + gf) * EMB + e4 * 4);
            uint2 u;
            u.x = pack2(v[0], v[1]);
            u.y = pack2(v[2], v[3]);
            *(uint2*)&elds[(f * BT + sb) * ESTR + e4 * 4] = u;
        }
    }
    __syncthreads();

    const int lane = threadIdx.x & 63;
    const int wid  = threadIdx.x >> 6;       // 0..7
    const int lo4  = lane & 15;
    const int hi4  = lane >> 4;

    // pair k (0..7) -> local fields (lr,lc) + global n ; wave-uniform
    auto pairK = [&](int k, int& lr, int& lc, int& nn) {
        int pr = wid + 8 * k;
        if (pr >= npr) pr -= npr;            // wrap: benign duplicate of another wave's pair
        if (type < 4) {
            int pig = (type & 1) * 60 + pr;  // triu16 index 0..119
            int r = 0;
            while (pig >= 15 - r) { pig -= 15 - r; ++r; }
            lr = r; lc = r + 1 + pig;
        } else {
            lr = pr >> 3; lc = 8 + (pr & 7);
        }
        const int R = lr + (lr < 8 ? bLo : bHi);
        const int C = lc + (lc < 8 ? bLo : bHi);
        nn = R * (63 - R) / 2 + (C - R - 1);
    };

    auto loadW = [&](bf16x8 (&wf)[4][2], int nn) {
        const bf16x8* wp = (const bf16x8*)(kb + (size_t)nn * 4096);
#pragma unroll
        for (int mh = 0; mh < 4; ++mh)
#pragma unroll
            for (int kc = 0; kc < 2; ++kc)
                wf[mh][kc] = wp[(mh * 2 + kc) * 64 + lane];   // 1KB coalesced
    };

    auto compute = [&](bf16x8 (&wf)[4][2], int lr, int lc, int nn) {
#pragma unroll
        for (int sub = 0; sub < 2; ++sub) {
            const int bb = sub * 16 + lo4;

            bf16x8 pf[2];
#pragma unroll
            for (int kc = 0; kc < 2; ++kc)
                pf[kc] = *(const bf16x8*)&elds[(lr * BT + bb) * ESTR + kc * 32 + hi4 * 8];

            f32x4 acc[4] = {f32x4{0,0,0,0}, f32x4{0,0,0,0},
                            f32x4{0,0,0,0}, f32x4{0,0,0,0}};
#pragma unroll
            for (int mh = 0; mh < 4; ++mh)
#pragma unroll
                for (int kc = 0; kc < 2; ++kc)
                    acc[mh] = __builtin_amdgcn_mfma_f32_16x16x32_bf16(
                        wf[mh][kc], pf[kc], acc[mh], 0, 0, 0);

            float val = 0.f;
#pragma unroll
            for (int mh = 0; mh < 4; ++mh) {
                const bf16x4 q = *(const bf16x4*)&elds[(lc * BT + bb) * ESTR + mh * 16 + hi4 * 4];
                val += acc[mh][0] * bf2f(q[0]) + acc[mh][1] * bf2f(q[1])
                     + acc[mh][2] * bf2f(q[2]) + acc[mh][3] * bf2f(q[3]);
            }
            val += __shfl_xor(val, 16, 64);
            val += __shfl_xor(val, 32, 64);
            if (lane < 16) out[(size_t)(b0 + bb) * NP + nn] = val;
        }
    };

    // ---- 8 pairs per wave, W ping-pong double-buffered (static buffers)
    bf16x8 wA[4][2], wB[4][2];
    int lrA, lcA, nA, lrB, lcB, nB;
    pairK(0, lrA, lcA, nA);
    loadW(wA, nA);
#pragma unroll
    for (int k = 0; k < 8; ++k) {
        if ((k & 1) == 0) {
            if (k < 7) { pairK(k + 1, lrB, lcB, nB); loadW(wB, nB); }
            compute(wA, lrA, lcA, nA);
        } else {
            if (k < 7) { pairK(k + 1, lrA, lcA, nA); loadW(wA, nA); }
            compute(wB, lrB, lcB, nB);
        }
    }
}

extern "C" void kernel_launch(void* const* d_in, const int* in_sizes, int n_in,
                              void* d_out, int out_size, void* d_ws, size_t ws_size,
                              hipStream_t stream) {
    const float* emb  = (const float*)d_in[0];   // 2048*32*64
    const float* kern = (const float*)d_in[1];   // 64*496*64
    float*       out  = (float*)d_out;           // 2048*496
    short*       kb   = (short*)d_ws;            // 496*4096 bf16 ~ 3.9MB

    cvt2<<<NP, 256, 0, stream>>>(kern, kb);            // 496 blocks
    opnl_main<<<8 * 64, 512, 0, stream>>>(emb, kb, out); // 512 blocks
}

// Round 7
// 29.172 us; speedup vs baseline: 3.9133x; 1.0426x over previous
//
#include <hip/hip_runtime.h>

// out[b,n] = q^T W_n p ; p=emb[b,R(n)], q=emb[b,C(n)], W_n=kern[:,n,:]
// R7: free staging + bank-balanced LDS.
//  - prep (single launch, grid-split):
//      part A: kern f32 [h][n][e] -> bf16 fragment order kb[n][8][64][8]
//      part B: emb f32 -> bf16 chunk-swizzled ebf[bt16][f][128 x 16B chunks],
//              chunk c = b'*8 + (e/8 ^ (b'&7))  (inverse-swizzled source)
//  - main: 8 balanced block types x 64 b-tiles (512 blocks, 512 thr, 2/CU).
//      stage = 8 global_load_lds(16B) per wave (linear dest) + 1 barrier.
//      swizzled ds_reads: p b128 8 words/bank, q b64 4 words/bank (floors).
//      W ping-pong double-buffered in VGPRs (1KB coalesced loads).

#define B_TOT 2048
#define NF    32
#define EMB   64
#define NP    496
#define BT    32

typedef short bf16x8 __attribute__((ext_vector_type(8)));
typedef short bf16x4 __attribute__((ext_vector_type(4)));
typedef float f32x4  __attribute__((ext_vector_type(4)));

static __device__ inline unsigned f2bf(float f) {          // RNE f32->bf16
    unsigned u = __builtin_bit_cast(unsigned, f);
    u += 0x7fffu + ((u >> 16) & 1u);
    return u >> 16;
}
static __device__ inline unsigned pack2(float lo, float hi) {
    return f2bf(lo) | (f2bf(hi) << 16);
}
static __device__ inline float bf2f(short s) {
    return __builtin_bit_cast(float, (unsigned)((unsigned short)s) << 16);
}

#define AS1 __attribute__((address_space(1)))
#define AS3 __attribute__((address_space(3)))

// ---- fused prep: blocks [0,496) = kern cvt ; blocks [496, 496+2048) = emb cvt
__global__ __launch_bounds__(256) void prep(const float* __restrict__ kern,
                                            const float* __restrict__ emb,
                                            short* __restrict__ kb,
                                            short* __restrict__ ebf) {
    __shared__ short w[EMB * 72];
    if (blockIdx.x < NP) {
        // kern [h][n][e] -> fragment order kb[n][frag][lane][8]
        const int n = blockIdx.x;
#pragma unroll
        for (int j = 0; j < 4; ++j) {
            const int idx = threadIdx.x + 256 * j;        // (h, e4)
            const int h = idx >> 4, e4 = idx & 15;
            const f32x4 v = *(const f32x4*)(kern + ((size_t)h * NP + n) * EMB + e4 * 4);
            uint2 u;
            u.x = pack2(v[0], v[1]);
            u.y = pack2(v[2], v[3]);
            *(uint2*)&w[h * 72 + e4 * 4] = u;
        }
        __syncthreads();
#pragma unroll
        for (int j = 0; j < 2; ++j) {
            const int u    = threadIdx.x + 256 * j;       // fragment-lane unit
            const int frag = u >> 6, l = u & 63;
            const int h  = (frag >> 1) * 16 + (l & 15);
            const int e0 = (frag & 1) * 32 + (l >> 4) * 8;
            const bf16x8 t = *(const bf16x8*)&w[h * 72 + e0];
            *(bf16x8*)(kb + (size_t)n * 4096 + u * 8) = t;
        }
    } else {
        // emb -> chunk-swizzled bf16: thread t writes 16B chunk t (coalesced),
        // reads emb[bt16*16+b'][f][ec*8..+7] with ec = x ^ (b'&7)
        const int t    = (blockIdx.x - NP) * 256 + threadIdx.x;  // 0..524287
        const int cidx = t & 127;
        const int f    = (t >> 7) & 31;
        const int bt16 = t >> 12;
        const int bp = cidx >> 3, x = cidx & 7;
        const int ec = x ^ (bp & 7);
        const float* src = emb + (((size_t)(bt16 * 16 + bp) * NF + f) * EMB + ec * 8);
        const f32x4 a = *(const f32x4*)src;
        const f32x4 b = *(const f32x4*)(src + 4);
        uint4 u;
        u.x = pack2(a[0], a[1]); u.y = pack2(a[2], a[3]);
        u.z = pack2(b[0], b[1]); u.w = pack2(b[2], b[3]);
        *(uint4*)(ebf + (size_t)t * 8) = u;
    }
}

__global__ __launch_bounds__(512, 4) void opnl_main(
    const short* __restrict__ ebf,   // [B/16][NF][128 chunks x 8 shorts] swizzled
    const short* __restrict__ kb,    // [NP][8][64][8] bf16 fragment order
    float* __restrict__ out)         // [B][NP] f32
{
    __shared__ short elds[16 * 2 * 1024];    // 32 segs x 2KB = 64KB

    const int type = blockIdx.x >> 6;        // 0..7
    const int bt   = blockIdx.x & 63;        // b-tile; bid%8 = bt%8 -> XCD share
    const int b0   = bt * BT;

    int bLo, bHi, npr;
    switch (type) {
        case 0: case 1: bLo = 0;  bHi = 0;  npr = 60; break;  // fields 0..15
        case 2: case 3: bLo = 16; bHi = 16; npr = 60; break;  // fields 16..31
        case 4:         bLo = 0;  bHi = 8;  npr = 64; break;  // O0 x O1
        case 5:         bLo = 8;  bHi = 16; npr = 64; break;  // O1 x O2
        case 6:         bLo = 0;  bHi = 16; npr = 64; break;  // O0 x O2
        default:        bLo = 8;  bHi = 8;  npr = 64; break;  // O1 x O1+... (8..23 cross per map)
    }

    const int lane = threadIdx.x & 63;
    const int wid  = threadIdx.x >> 6;       // 0..7
    const int lo4  = lane & 15;
    const int hi4  = lane >> 4;

    // ---- stage: wave w copies segs 4w..4w+3 (seg = lf*2+sub), 2x 1KB each
#pragma unroll
    for (int i = 0; i < 4; ++i) {
        const int s   = wid * 4 + i;
        const int lf  = s >> 1, sub = s & 1;
        const int gf  = lf + (lf < 8 ? bLo : bHi);
        const short* src = ebf + ((size_t)((bt * 2 + sub) * 32 + gf)) * 1024;
        __builtin_amdgcn_global_load_lds((const AS1 void*)(src + lane * 8),
                                         (AS3 void*)&elds[s * 1024], 16, 0, 0);
        __builtin_amdgcn_global_load_lds((const AS1 void*)(src + 512 + lane * 8),
                                         (AS3 void*)&elds[s * 1024 + 512], 16, 0, 0);
    }
    __syncthreads();   // drains vmcnt (compiler-inserted) + barrier

    // pair k (0..7) -> local fields (lr,lc) + global n ; wave-uniform
    auto pairK = [&](int k, int& lr, int& lc, int& nn) {
        int pr = wid + 8 * k;
        if (pr >= npr) pr -= npr;            // wrap: benign duplicate write
        if (type < 4) {
            int pig = (type & 1) * 60 + pr;  // triu16 index 0..119
            int r = 0;
            while (pig >= 15 - r) { pig -= 15 - r; ++r; }
            lr = r; lc = r + 1 + pig;
        } else {
            lr = pr >> 3; lc = 8 + (pr & 7);
        }
        const int R = lr + (lr < 8 ? bLo : bHi);
        const int C = lc + (lc < 8 ? bLo : bHi);
        nn = R * (63 - R) / 2 + (C - R - 1);
    };

    auto loadW = [&](bf16x8 (&wf)[4][2], int nn) {
        const bf16x8* wp = (const bf16x8*)(kb + (size_t)nn * 4096);
#pragma unroll
        for (int mh = 0; mh < 4; ++mh)
#pragma unroll
            for (int kc = 0; kc < 2; ++kc)
                wf[mh][kc] = wp[(mh * 2 + kc) * 64 + lane];   // 1KB coalesced
    };

    auto compute = [&](bf16x8 (&wf)[4][2], int lr, int lc, int nn) {
#pragma unroll
        for (int sub = 0; sub < 2; ++sub) {
            const int bb = sub * 16 + lo4;

            bf16x8 pf[2];
#pragma unroll
            for (int kc = 0; kc < 2; ++kc)
                pf[kc] = *(const bf16x8*)
                    &elds[(lr * 2 + sub) * 1024 +
                          (lo4 * 8 + (((kc * 4 + hi4) ^ (lo4 & 7)))) * 8];

            f32x4 acc[4] = {f32x4{0,0,0,0}, f32x4{0,0,0,0},
                            f32x4{0,0,0,0}, f32x4{0,0,0,0}};
#pragma unroll
            for (int mh = 0; mh < 4; ++mh)
#pragma unroll
                for (int kc = 0; kc < 2; ++kc)
                    acc[mh] = __builtin_amdgcn_mfma_f32_16x16x32_bf16(
                        wf[mh][kc], pf[kc], acc[mh], 0, 0, 0);

            float val = 0.f;
#pragma unroll
            for (int mh = 0; mh < 4; ++mh) {
                const bf16x4 q = *(const bf16x4*)
                    &elds[(lc * 2 + sub) * 1024 +
                          (lo4 * 8 + (((mh * 2 + (hi4 >> 1)) ^ (lo4 & 7)))) * 8 +
                          (hi4 & 1) * 4];
                val += acc[mh][0] * bf2f(q[0]) + acc[mh][1] * bf2f(q[1])
                     + acc[mh][2] * bf2f(q[2]) + acc[mh][3] * bf2f(q[3]);
            }
            val += __shfl_xor(val, 16, 64);
            val += __shfl_xor(val, 32, 64);
            if (lane < 16) out[(size_t)(b0 + bb) * NP + nn] = val;
        }
    };

    // ---- 8 pairs per wave, W ping-pong double-buffered (static buffers)
    bf16x8 wA[4][2], wB[4][2];
    int lrA, lcA, nA, lrB, lcB, nB;
    pairK(0, lrA, lcA, nA);
    loadW(wA, nA);
#pragma unroll
    for (int k = 0; k < 8; ++k) {
        if ((k & 1) == 0) {
            if (k < 7) { pairK(k + 1, lrB, lcB, nB); loadW(wB, nB); }
            compute(wA, lrA, lcA, nA);
        } else {
            if (k < 7) { pairK(k + 1, lrA, lcA, nA); loadW(wA, nA); }
            compute(wB, lrB, lcB, nB);
        }
    }
}

extern "C" void kernel_launch(void* const* d_in, const int* in_sizes, int n_in,
                              void* d_out, int out_size, void* d_ws, size_t ws_size,
                              hipStream_t stream) {
    const float* emb  = (const float*)d_in[0];   // 2048*32*64
    const float* kern = (const float*)d_in[1];   // 64*496*64
    float*       out  = (float*)d_out;           // 2048*496

    short* kb  = (short*)d_ws;                          // 496*4096 bf16 ~3.9MB
    short* ebf = (short*)((char*)d_ws + (4 << 20));     // 2048*32*64 bf16 = 8MB

    prep<<<NP + (B_TOT * NF * EMB / 8) / 256, 256, 0, stream>>>(kern, emb, kb, ebf);
    opnl_main<<<8 * 64, 512, 0, stream>>>(ebf, kb, out);   // 512 blocks
}